// Round 22
// baseline (72.373 us; speedup 1.0000x reference)
//
#include <hip/hip_runtime.h>
#include <hip/hip_bf16.h>

typedef __attribute__((ext_vector_type(8))) short bf16x8;
typedef __attribute__((ext_vector_type(4))) float f32x4;

#define QSCALE 0.088388347648318447f   /* 1/sqrt(128) */

__device__ __forceinline__ unsigned short f2bf(float f) {
  __hip_bfloat16 h = __float2bfloat16(f);
  unsigned short u;
  __builtin_memcpy(&u, &h, 2);
  return u;
}
__device__ __forceinline__ float bf2f(unsigned short u) {
  unsigned int x = ((unsigned int)u) << 16;
  float f; __builtin_memcpy(&f, &x, 4);
  return f;
}

__device__ __forceinline__ void gload_lds16(void* lds, const void* g) {
  __builtin_amdgcn_global_load_lds(
      (const __attribute__((address_space(1))) unsigned int*)g,
      (__attribute__((address_space(3))) unsigned int*)lds, 16, 0, 0);
}

// ---- W^T build only (X conversion folded into proj_gemm, R22) ----
__global__ __launch_bounds__(256) void cvt_w(const float* __restrict__ Wq,
                                             const float* __restrict__ Wk,
                                             const float* __restrict__ Wv,
                                             unsigned short* __restrict__ Wt) {
  int idx = blockIdx.x * 256 + threadIdx.x;   // [0, 393216)
  int n = idx >> 10, d = idx & 1023;
  const float* W = (n < 128) ? Wq : (n < 256 ? Wk : Wv);
  float v = W[d * 128 + (n & 127)];
  if (n < 128) v *= QSCALE;
  Wt[idx] = f2bf(v);
}

// ---- fused QKV projection: fp32 X @ bf16 W^T, 64x64 tiles ----
// R22: reads X fp32 directly (deletes cvt_x's 48MB round-trip). XCD-local
// bid mapping: mt=bid&127, nt=bid>>7 -> the 6 blocks sharing m-slab mt all
// have bid==mt (mod 8) -> same XCD, co-resident (3 blocks/CU) -> A-slab
// fetched from HBM once, 5x L2-hits. (R11's 100MB FETCH failure was the
// OLD mapping putting those 6 blocks on 6 different XCDs.)
__global__ __launch_bounds__(256) void proj_gemm(
    const float* __restrict__ X, const unsigned short* __restrict__ Wt,
    const float* __restrict__ bq, const float* __restrict__ bk, const float* __restrict__ bv,
    unsigned short* __restrict__ Qb, unsigned short* __restrict__ Kb,
    unsigned short* __restrict__ Vt) {
  __shared__ unsigned short sA[64 * 64];
  __shared__ unsigned short sB[64 * 64];
  const int mt = blockIdx.x & 127;
  const int nt = blockIdx.x >> 7;
  const int m0 = mt * 64;
  const int n0 = nt * 64;
  const int tid = threadIdx.x;
  const int lane = tid & 63;
  const int w = tid >> 6;
  const int r = lane & 15, g = lane >> 4;
  const int wm = (w >> 1) * 32, wn = (w & 1) * 32;

  f32x4 acc[2][2];
  #pragma unroll
  for (int mi = 0; mi < 2; ++mi)
    #pragma unroll
    for (int ni = 0; ni < 2; ++ni)
      acc[mi][ni] = (f32x4){0.f, 0.f, 0.f, 0.f};

  const char* Bb = (const char*)Wt;
  char* sBb = (char*)sB;

  for (int k0 = 0; k0 < 1024; k0 += 64) {
    // stage B: bf16 via global_load_lds (async)
    #pragma unroll
    for (int j = 0; j < 2; ++j) {
      int f = j * 4096 + tid * 16;
      int row = f >> 7, colb = f & 127;
      gload_lds16(sBb + f, Bb + ((size_t)(n0 + row) * 1024 + k0) * 2 + colb);
    }
    // stage A: 16 fp32/thread -> bf16 -> LDS (reg-staged)
    #pragma unroll
    for (int it2 = 0; it2 < 4; ++it2) {
      const int f = it2 * 1024 + tid * 4;          // float index in 64x64 tile
      const int row = f >> 6, col = f & 63;
      const float4 v = *reinterpret_cast<const float4*>(
          X + (size_t)(m0 + row) * 1024 + k0 + col);
      ushort4 o4;
      o4.x = f2bf(v.x); o4.y = f2bf(v.y); o4.z = f2bf(v.z); o4.w = f2bf(v.w);
      *reinterpret_cast<ushort4*>(&sA[row * 64 + col]) = o4;
    }
    __syncthreads();
    #pragma unroll
    for (int kk = 0; kk < 2; ++kk) {
      bf16x8 af[2], bfr[2];
      #pragma unroll
      for (int mi = 0; mi < 2; ++mi)
        af[mi] = *reinterpret_cast<const bf16x8*>(sA + (wm + mi * 16 + r) * 64 + kk * 32 + g * 8);
      #pragma unroll
      for (int ni = 0; ni < 2; ++ni)
        bfr[ni] = *reinterpret_cast<const bf16x8*>(sB + (wn + ni * 16 + r) * 64 + kk * 32 + g * 8);
      #pragma unroll
      for (int mi = 0; mi < 2; ++mi)
        #pragma unroll
        for (int ni = 0; ni < 2; ++ni)
          acc[mi][ni] = __builtin_amdgcn_mfma_f32_16x16x32_bf16(af[mi], bfr[ni], acc[mi][ni], 0, 0, 0);
    }
    __syncthreads();
  }

  const float* bias = (nt < 2) ? bq : (nt < 4 ? bk : bv);
  const float bsc = (nt < 2) ? QSCALE : 1.0f;
  #pragma unroll
  for (int mi = 0; mi < 2; ++mi) {
    #pragma unroll
    for (int ni = 0; ni < 2; ++ni) {
      const int colg = n0 + wn + ni * 16 + r;      // [0,384)
      const int colm = colg & 127;
      const float bias_v = bias[colm] * bsc;
      #pragma unroll
      for (int e = 0; e < 4; ++e) {
        const int row = m0 + wm + mi * 16 + g * 4 + e;   // [0,8192)
        const unsigned short hh = f2bf(acc[mi][ni][e] + bias_v);
        if (nt < 2) Qb[(size_t)row * 128 + colm] = hh;
        else if (nt < 4) Kb[(size_t)row * 128 + colm] = hh;
        else {
          const int bb = row >> 11, s = row & 2047;
          Vt[((size_t)bb * 128 + colm) * 2048 + s] = hh;
        }
      }
    }
  }
}

// ---- flash attention: block-shared LDS-staged K/V (R21 version) ----
__global__ __launch_bounds__(256, 4) void attn(
    const unsigned short* __restrict__ Qb, const unsigned short* __restrict__ Kb,
    const unsigned short* __restrict__ Vt,
    unsigned short* __restrict__ po, float* __restrict__ pl) {
  __shared__ char sK[2][8192];
  __shared__ char sV[2][8192];
  __shared__ unsigned short pbuf_s[4][512];
  const int tid = threadIdx.x;
  const int lane = tid & 63;
  const int w = tid >> 6;                  // [0,4)
  const int r = lane & 15, g = lane >> 4;
  const int sig = blockIdx.x & 7;
  const int b = (blockIdx.x >> 3) & 3;
  const int p = (blockIdx.x >> 5) & 7;     // [0,8)
  const int h2 = blockIdx.x >> 8;          // [0,2)

  const char* Kg = (const char*)(Kb + (size_t)b * 2048 * 128);
  const char* Vg = (const char*)(Vt + (size_t)b * 128 * 2048);
  unsigned short* pbuf = pbuf_s[w];

  const int kr0 = tid >> 4;            // [0,16)
  const int kr1 = 16 + (tid >> 4);     // [16,32)
  const int kc0 = ((tid & 15) * 16) ^ ((kr0 & 7) * 16);
  const int kc1 = ((tid & 15) * 16) ^ ((kr1 & 7) * 16);
  const int vr0 = tid >> 2;            // [0,64)
  const int vr1 = 64 + (tid >> 2);     // [64,128)
  const int vc0 = ((tid & 3) * 16) ^ ((vr0 & 3) * 16);
  const int vc1 = ((tid & 3) * 16) ^ ((vr1 & 3) * 16);

  for (int phase = 0; phase < 2; ++phase) {
    const int t = phase ? (15 - p) : p;
    const int sb = t * 128 + h2 * 64;
    const int ntiles = (2048 - sb) >> 5;
    const int q0w = t * 128 + h2 * 64 + w * 16;

    const unsigned short* Q = Qb + (size_t)(b * 2048 + q0w) * 128;
    bf16x8 qf[4];
    #pragma unroll
    for (int kk = 0; kk < 4; ++kk)
      qf[kk] = *reinterpret_cast<const bf16x8*>(Q + r * 128 + kk * 32 + g * 8);

    f32x4 o[8];
    #pragma unroll
    for (int ni = 0; ni < 8; ++ni) o[ni] = (f32x4){0.f, 0.f, 0.f, 0.f};
    float l[4];
    #pragma unroll
    for (int e = 0; e < 4; ++e) l[e] = 0.f;

    const int nT = (ntiles > sig) ? ((ntiles - sig + 7) >> 3) : 0;

    if (nT > 0) {
      const int s0 = sb + (sig << 5);
      gload_lds16(&sK[0][tid * 16], Kg + (size_t)(s0 + kr0) * 256 + kc0);
      gload_lds16(&sK[0][4096 + tid * 16], Kg + (size_t)(s0 + kr1) * 256 + kc1);
      gload_lds16(&sV[0][tid * 16], Vg + (size_t)vr0 * 4096 + (size_t)s0 * 2 + vc0);
      gload_lds16(&sV[0][4096 + tid * 16], Vg + (size_t)vr1 * 4096 + (size_t)s0 * 2 + vc1);
    }
    for (int it = 0; it < nT; ++it) {
      const int cur = it & 1;
      const int s0 = sb + ((sig + (it << 3)) << 5);
      asm volatile("s_waitcnt vmcnt(0) lgkmcnt(0)" ::: "memory");
      __builtin_amdgcn_sched_barrier(0);
      asm volatile("s_barrier" ::: "memory");
      if (it + 1 < nT) {
        const int s1 = s0 + 256;
        gload_lds16(&sK[cur ^ 1][tid * 16], Kg + (size_t)(s1 + kr0) * 256 + kc0);
        gload_lds16(&sK[cur ^ 1][4096 + tid * 16], Kg + (size_t)(s1 + kr1) * 256 + kc1);
        gload_lds16(&sV[cur ^ 1][tid * 16], Vg + (size_t)vr0 * 4096 + (size_t)s1 * 2 + vc0);
        gload_lds16(&sV[cur ^ 1][4096 + tid * 16], Vg + (size_t)vr1 * 4096 + (size_t)s1 * 2 + vc1);
      }

      f32x4 st[2];
      #pragma unroll
      for (int sj = 0; sj < 2; ++sj) {
        f32x4 a = (f32x4){0.f, 0.f, 0.f, 0.f};
        #pragma unroll
        for (int kk = 0; kk < 4; ++kk) {
          const bf16x8 kf = *reinterpret_cast<const bf16x8*>(
              &sK[cur][(sj * 16 + r) * 256 + (((kk * 64 + g * 16) ^ ((r & 7) * 16)))]);
          a = __builtin_amdgcn_mfma_f32_16x16x32_bf16(qf[kk], kf, a, 0, 0, 0);
        }
        st[sj] = a;
      }
      #pragma unroll
      for (int sj = 0; sj < 2; ++sj) {
        const int s = s0 + sj * 16 + r;
        #pragma unroll
        for (int e = 0; e < 4; ++e) {
          const int q = q0w + g * 4 + e;
          st[sj][e] = (s <= q) ? 0.f : __expf(st[sj][e]);
        }
      }
      #pragma unroll
      for (int e = 0; e < 4; ++e) l[e] += st[0][e] + st[1][e];

      #pragma unroll
      for (int sj = 0; sj < 2; ++sj)
        #pragma unroll
        for (int e = 0; e < 4; ++e)
          pbuf[(g * 4 + e) * 32 + sj * 16 + r] = f2bf(st[sj][e]);
      asm volatile("s_waitcnt lgkmcnt(0)" ::: "memory");
      __builtin_amdgcn_sched_barrier(0);
      const bf16x8 pa = *reinterpret_cast<const bf16x8*>(&pbuf[r * 32 + g * 8]);

      #pragma unroll
      for (int ni = 0; ni < 8; ++ni) {
        const bf16x8 vf = *reinterpret_cast<const bf16x8*>(
            &sV[cur][(ni * 16 + r) * 64 + ((g * 16) ^ ((r & 3) * 16))]);
        o[ni] = __builtin_amdgcn_mfma_f32_16x16x32_bf16(pa, vf, o[ni], 0, 0, 0);
      }
    }

    #pragma unroll
    for (int off = 1; off < 16; off <<= 1)
      #pragma unroll
      for (int e = 0; e < 4; ++e)
        l[e] += __shfl_xor(l[e], off, 64);

    const size_t pb = ((size_t)((b * 16 + t) * 8 + sig)) * 16384;
    const int rbase = h2 * 64 + w * 16;
    #pragma unroll
    for (int ni = 0; ni < 8; ++ni)
      #pragma unroll
      for (int e = 0; e < 4; ++e)
        po[pb + (size_t)(rbase + g * 4 + e) * 128 + ni * 16 + r] = f2bf(o[ni][e]);
    if (r == 0) {
      #pragma unroll
      for (int e = 0; e < 4; ++e)
        pl[((size_t)((b * 16 + t) * 8 + sig)) * 128 + rbase + g * 4 + e] = l[e];
    }
    __syncthreads();
  }
}

// ---- fused epilogue: blocks [0,4096) merge the 8 sigma-partials
//      (skipping q==2047); blocks [4096,4224) write row 2047 = mean(V) ----
__global__ __launch_bounds__(256) void combine(const unsigned short* __restrict__ po,
                                               const float* __restrict__ pl,
                                               const unsigned short* __restrict__ Vt,
                                               float* __restrict__ out) {
  const int bid = blockIdx.x;
  if (bid < 4096) {
    const int idx = bid * 256 + threadIdx.x;   // [0, 1048576)
    const int d = idx & 127;
    const int gq = idx >> 7;          // [0, 8192)
    const int b = gq >> 11, q = gq & 2047;
    if (q == 2047) return;            // written by the lastrow branch
    const int qt = q >> 7, row = q & 127;
    const size_t base = (size_t)(b * 16 + qt) * 8;
    float o = 0.f, l = 0.f;
    #pragma unroll
    for (int s = 0; s < 8; ++s) {
      o += bf2f(po[(base + s) * 16384 + row * 128 + d]);
      l += pl[(base + s) * 128 + row];
    }
    out[idx] = (l > 0.f) ? o / l : 0.f;
  } else {
    // lastrow: mean(V) (reference: all scores -1e9 in fp32 -> uniform softmax)
    const int seg = bid - 4096;       // [0,128)
    const int b = seg >> 5;
    const int w = threadIdx.x >> 6;
    const int lane = threadIdx.x & 63;
    const int dk = (seg & 31) * 4 + w;
    const unsigned short* row = Vt + (size_t)(b * 128 + dk) * 2048;
    float s = 0.f;
    for (int i = lane; i < 2048; i += 64) s += bf2f(row[i]);
    #pragma unroll
    for (int off = 32; off > 0; off >>= 1) s += __shfl_down(s, off, 64);
    if (lane == 0) out[(size_t)(b * 2048 + 2047) * 128 + dk] = s * (1.0f / 2048.0f);
  }
}

extern "C" void kernel_launch(void* const* d_in, const int* in_sizes, int n_in,
                              void* d_out, int out_size, void* d_ws, size_t ws_size,
                              hipStream_t stream) {
  const float* x  = (const float*)d_in[0];
  const float* Wq = (const float*)d_in[1];
  const float* bq = (const float*)d_in[2];
  const float* Wk = (const float*)d_in[3];
  const float* bk = (const float*)d_in[4];
  const float* Wv = (const float*)d_in[5];
  const float* bv = (const float*)d_in[6];
  float* out = (float*)d_out;
  char* ws = (char*)d_ws;
  // workspace layout (bytes), no aliasing:
  //   [16,17MB): Wt | [17,19): Qb | [19,21): Kb | [21,23): Vt
  //   [24,40MB): po (bf16) | [48MB,+64KB): pl (fp32)
  unsigned short* Wt = (unsigned short*)(ws + (size_t)(16u << 20));
  unsigned short* Qb = (unsigned short*)(ws + (size_t)(17u << 20));
  unsigned short* Kb = (unsigned short*)(ws + (size_t)(19u << 20));
  unsigned short* Vt = (unsigned short*)(ws + (size_t)(21u << 20));
  unsigned short* po = (unsigned short*)(ws + (size_t)(24u << 20));
  float* pl = (float*)(ws + (size_t)(48u << 20));

  hipLaunchKernelGGL(cvt_w, dim3(1536), dim3(256), 0, stream, Wq, Wk, Wv, Wt);
  hipLaunchKernelGGL(proj_gemm, dim3(768), dim3(256), 0, stream,
                     x, Wt, bq, bk, bv, Qb, Kb, Vt);
  hipLaunchKernelGGL(attn, dim3(512), dim3(256), 0, stream, Qb, Kb, Vt, po, pl);
  hipLaunchKernelGGL(combine, dim3(4224), dim3(256), 0, stream, po, pl, Vt, out);
}

// Round 23
// 61.342 us; speedup vs baseline: 1.1798x; 1.1798x over previous
//
#include <hip/hip_runtime.h>
#include <hip/hip_bf16.h>

typedef __attribute__((ext_vector_type(8))) short bf16x8;
typedef __attribute__((ext_vector_type(4))) float f32x4;

#define QSCALE 0.088388347648318447f   /* 1/sqrt(128) */

__device__ __forceinline__ unsigned short f2bf(float f) {
  __hip_bfloat16 h = __float2bfloat16(f);
  unsigned short u;
  __builtin_memcpy(&u, &h, 2);
  return u;
}
__device__ __forceinline__ float bf2f(unsigned short u) {
  unsigned int x = ((unsigned int)u) << 16;
  float f; __builtin_memcpy(&f, &x, 4);
  return f;
}

__device__ __forceinline__ void gload_lds16(void* lds, const void* g) {
  __builtin_amdgcn_global_load_lds(
      (const __attribute__((address_space(1))) unsigned int*)g,
      (__attribute__((address_space(3))) unsigned int*)lds, 16, 0, 0);
}

// ---- W^T build only (X conversion folded into proj_gemm) ----
__global__ __launch_bounds__(256) void cvt_w(const float* __restrict__ Wq,
                                             const float* __restrict__ Wk,
                                             const float* __restrict__ Wv,
                                             unsigned short* __restrict__ Wt) {
  int idx = blockIdx.x * 256 + threadIdx.x;   // [0, 393216)
  int n = idx >> 10, d = idx & 1023;
  const float* W = (n < 128) ? Wq : (n < 256 ? Wk : Wv);
  float v = W[d * 128 + (n & 127)];
  if (n < 128) v *= QSCALE;
  Wt[idx] = f2bf(v);
}

// ---- fused QKV projection: fp32 X @ bf16 W^T, 64x64 tiles ----
// R23: A staged as fp32 via ASYNC global_load_lds (R22's reg-staged sync
// chain was the 49us culprit — FETCH was fine at 19.5MB). Source-side XOR
// swizzle (chunk ^= row&7, rule #21) -> fragment ds_read_b128 pairs land
// 2-way conflict-free; fp32->bf16 cvt at fragment-read time overlaps MFMA.
// XCD-local mapping kept: mt=bid&127 -> the 6 blocks sharing an m-slab sit
// on one XCD (proven: FETCH 100->19.5MB).
__global__ __launch_bounds__(256) void proj_gemm(
    const float* __restrict__ X, const unsigned short* __restrict__ Wt,
    const float* __restrict__ bq, const float* __restrict__ bk, const float* __restrict__ bv,
    unsigned short* __restrict__ Qb, unsigned short* __restrict__ Kb,
    unsigned short* __restrict__ Vt) {
  __shared__ float sAf[64 * 64];            // 16KB fp32 A-tile (swizzled layout)
  __shared__ unsigned short sB[64 * 64];    // 8KB bf16 B-tile
  const int mt = blockIdx.x & 127;
  const int nt = blockIdx.x >> 7;
  const int m0 = mt * 64;
  const int n0 = nt * 64;
  const int tid = threadIdx.x;
  const int lane = tid & 63;
  const int w = tid >> 6;
  const int r = lane & 15, g = lane >> 4;
  const int wm = (w >> 1) * 32, wn = (w & 1) * 32;

  f32x4 acc[2][2];
  #pragma unroll
  for (int mi = 0; mi < 2; ++mi)
    #pragma unroll
    for (int ni = 0; ni < 2; ++ni)
      acc[mi][ni] = (f32x4){0.f, 0.f, 0.f, 0.f};

  const char* Bb = (const char*)Wt;
  char* sAb = (char*)sAf;
  char* sBb = (char*)sB;

  // A staging source components (4 chunks/thread, 16B each).
  // LDS linear pos f -> (row = f>>8, chunk c = (f>>4)&15); source column
  // chunk = c ^ (row&7)  (inverse of the read-side swizzle).
  int arow_s[4], acol_s[4];
  #pragma unroll
  for (int j = 0; j < 4; ++j) {
    const int f = j * 4096 + tid * 16;
    const int row = f >> 8;
    const int c = (f >> 4) & 15;
    arow_s[j] = row;
    acol_s[j] = (c ^ (row & 7)) * 4;      // float index within 64-col tile
  }

  for (int k0 = 0; k0 < 1024; k0 += 64) {
    // stage A: fp32, async, linear dest + pre-swizzled source
    #pragma unroll
    for (int j = 0; j < 4; ++j)
      gload_lds16(sAb + j * 4096 + tid * 16,
                  X + (size_t)(m0 + arow_s[j]) * 1024 + k0 + acol_s[j]);
    // stage B: bf16, async, linear
    #pragma unroll
    for (int j = 0; j < 2; ++j) {
      int f = j * 4096 + tid * 16;
      int row = f >> 7, colb = f & 127;
      gload_lds16(sBb + f, Bb + ((size_t)(n0 + row) * 1024 + k0) * 2 + colb);
    }
    __syncthreads();
    #pragma unroll
    for (int kk = 0; kk < 2; ++kk) {
      bf16x8 af[2], bfr[2];
      #pragma unroll
      for (int mi = 0; mi < 2; ++mi) {
        const int arow = wm + mi * 16 + r;
        const int sw = arow & 7;
        const int c0 = kk * 8 + g * 2;
        const float4 lo = *reinterpret_cast<const float4*>(
            &sAf[arow * 64 + ((c0 ^ sw) * 4)]);
        const float4 hi = *reinterpret_cast<const float4*>(
            &sAf[arow * 64 + (((c0 + 1) ^ sw) * 4)]);
        union { unsigned short h[8]; bf16x8 v; } u;
        u.h[0] = f2bf(lo.x); u.h[1] = f2bf(lo.y);
        u.h[2] = f2bf(lo.z); u.h[3] = f2bf(lo.w);
        u.h[4] = f2bf(hi.x); u.h[5] = f2bf(hi.y);
        u.h[6] = f2bf(hi.z); u.h[7] = f2bf(hi.w);
        af[mi] = u.v;
      }
      #pragma unroll
      for (int ni = 0; ni < 2; ++ni)
        bfr[ni] = *reinterpret_cast<const bf16x8*>(sB + (wn + ni * 16 + r) * 64 + kk * 32 + g * 8);
      #pragma unroll
      for (int mi = 0; mi < 2; ++mi)
        #pragma unroll
        for (int ni = 0; ni < 2; ++ni)
          acc[mi][ni] = __builtin_amdgcn_mfma_f32_16x16x32_bf16(af[mi], bfr[ni], acc[mi][ni], 0, 0, 0);
    }
    __syncthreads();
  }

  const float* bias = (nt < 2) ? bq : (nt < 4 ? bk : bv);
  const float bsc = (nt < 2) ? QSCALE : 1.0f;
  #pragma unroll
  for (int mi = 0; mi < 2; ++mi) {
    #pragma unroll
    for (int ni = 0; ni < 2; ++ni) {
      const int colg = n0 + wn + ni * 16 + r;      // [0,384)
      const int colm = colg & 127;
      const float bias_v = bias[colm] * bsc;
      #pragma unroll
      for (int e = 0; e < 4; ++e) {
        const int row = m0 + wm + mi * 16 + g * 4 + e;   // [0,8192)
        const unsigned short hh = f2bf(acc[mi][ni][e] + bias_v);
        if (nt < 2) Qb[(size_t)row * 128 + colm] = hh;
        else if (nt < 4) Kb[(size_t)row * 128 + colm] = hh;
        else {
          const int bb = row >> 11, s = row & 2047;
          Vt[((size_t)bb * 128 + colm) * 2048 + s] = hh;
        }
      }
    }
  }
}

// ---- flash attention: block-shared LDS-staged K/V (R21 version) ----
__global__ __launch_bounds__(256, 4) void attn(
    const unsigned short* __restrict__ Qb, const unsigned short* __restrict__ Kb,
    const unsigned short* __restrict__ Vt,
    unsigned short* __restrict__ po, float* __restrict__ pl) {
  __shared__ char sK[2][8192];
  __shared__ char sV[2][8192];
  __shared__ unsigned short pbuf_s[4][512];
  const int tid = threadIdx.x;
  const int lane = tid & 63;
  const int w = tid >> 6;                  // [0,4)
  const int r = lane & 15, g = lane >> 4;
  const int sig = blockIdx.x & 7;
  const int b = (blockIdx.x >> 3) & 3;
  const int p = (blockIdx.x >> 5) & 7;     // [0,8)
  const int h2 = blockIdx.x >> 8;          // [0,2)

  const char* Kg = (const char*)(Kb + (size_t)b * 2048 * 128);
  const char* Vg = (const char*)(Vt + (size_t)b * 128 * 2048);
  unsigned short* pbuf = pbuf_s[w];

  const int kr0 = tid >> 4;            // [0,16)
  const int kr1 = 16 + (tid >> 4);     // [16,32)
  const int kc0 = ((tid & 15) * 16) ^ ((kr0 & 7) * 16);
  const int kc1 = ((tid & 15) * 16) ^ ((kr1 & 7) * 16);
  const int vr0 = tid >> 2;            // [0,64)
  const int vr1 = 64 + (tid >> 2);     // [64,128)
  const int vc0 = ((tid & 3) * 16) ^ ((vr0 & 3) * 16);
  const int vc1 = ((tid & 3) * 16) ^ ((vr1 & 3) * 16);

  for (int phase = 0; phase < 2; ++phase) {
    const int t = phase ? (15 - p) : p;
    const int sb = t * 128 + h2 * 64;
    const int ntiles = (2048 - sb) >> 5;
    const int q0w = t * 128 + h2 * 64 + w * 16;

    const unsigned short* Q = Qb + (size_t)(b * 2048 + q0w) * 128;
    bf16x8 qf[4];
    #pragma unroll
    for (int kk = 0; kk < 4; ++kk)
      qf[kk] = *reinterpret_cast<const bf16x8*>(Q + r * 128 + kk * 32 + g * 8);

    f32x4 o[8];
    #pragma unroll
    for (int ni = 0; ni < 8; ++ni) o[ni] = (f32x4){0.f, 0.f, 0.f, 0.f};
    float l[4];
    #pragma unroll
    for (int e = 0; e < 4; ++e) l[e] = 0.f;

    const int nT = (ntiles > sig) ? ((ntiles - sig + 7) >> 3) : 0;

    if (nT > 0) {
      const int s0 = sb + (sig << 5);
      gload_lds16(&sK[0][tid * 16], Kg + (size_t)(s0 + kr0) * 256 + kc0);
      gload_lds16(&sK[0][4096 + tid * 16], Kg + (size_t)(s0 + kr1) * 256 + kc1);
      gload_lds16(&sV[0][tid * 16], Vg + (size_t)vr0 * 4096 + (size_t)s0 * 2 + vc0);
      gload_lds16(&sV[0][4096 + tid * 16], Vg + (size_t)vr1 * 4096 + (size_t)s0 * 2 + vc1);
    }
    for (int it = 0; it < nT; ++it) {
      const int cur = it & 1;
      const int s0 = sb + ((sig + (it << 3)) << 5);
      asm volatile("s_waitcnt vmcnt(0) lgkmcnt(0)" ::: "memory");
      __builtin_amdgcn_sched_barrier(0);
      asm volatile("s_barrier" ::: "memory");
      if (it + 1 < nT) {
        const int s1 = s0 + 256;
        gload_lds16(&sK[cur ^ 1][tid * 16], Kg + (size_t)(s1 + kr0) * 256 + kc0);
        gload_lds16(&sK[cur ^ 1][4096 + tid * 16], Kg + (size_t)(s1 + kr1) * 256 + kc1);
        gload_lds16(&sV[cur ^ 1][tid * 16], Vg + (size_t)vr0 * 4096 + (size_t)s1 * 2 + vc0);
        gload_lds16(&sV[cur ^ 1][4096 + tid * 16], Vg + (size_t)vr1 * 4096 + (size_t)s1 * 2 + vc1);
      }

      f32x4 st[2];
      #pragma unroll
      for (int sj = 0; sj < 2; ++sj) {
        f32x4 a = (f32x4){0.f, 0.f, 0.f, 0.f};
        #pragma unroll
        for (int kk = 0; kk < 4; ++kk) {
          const bf16x8 kf = *reinterpret_cast<const bf16x8*>(
              &sK[cur][(sj * 16 + r) * 256 + (((kk * 64 + g * 16) ^ ((r & 7) * 16)))]);
          a = __builtin_amdgcn_mfma_f32_16x16x32_bf16(qf[kk], kf, a, 0, 0, 0);
        }
        st[sj] = a;
      }
      #pragma unroll
      for (int sj = 0; sj < 2; ++sj) {
        const int s = s0 + sj * 16 + r;
        #pragma unroll
        for (int e = 0; e < 4; ++e) {
          const int q = q0w + g * 4 + e;
          st[sj][e] = (s <= q) ? 0.f : __expf(st[sj][e]);
        }
      }
      #pragma unroll
      for (int e = 0; e < 4; ++e) l[e] += st[0][e] + st[1][e];

      #pragma unroll
      for (int sj = 0; sj < 2; ++sj)
        #pragma unroll
        for (int e = 0; e < 4; ++e)
          pbuf[(g * 4 + e) * 32 + sj * 16 + r] = f2bf(st[sj][e]);
      asm volatile("s_waitcnt lgkmcnt(0)" ::: "memory");
      __builtin_amdgcn_sched_barrier(0);
      const bf16x8 pa = *reinterpret_cast<const bf16x8*>(&pbuf[r * 32 + g * 8]);

      #pragma unroll
      for (int ni = 0; ni < 8; ++ni) {
        const bf16x8 vf = *reinterpret_cast<const bf16x8*>(
            &sV[cur][(ni * 16 + r) * 64 + ((g * 16) ^ ((r & 3) * 16))]);
        o[ni] = __builtin_amdgcn_mfma_f32_16x16x32_bf16(pa, vf, o[ni], 0, 0, 0);
      }
    }

    #pragma unroll
    for (int off = 1; off < 16; off <<= 1)
      #pragma unroll
      for (int e = 0; e < 4; ++e)
        l[e] += __shfl_xor(l[e], off, 64);

    const size_t pb = ((size_t)((b * 16 + t) * 8 + sig)) * 16384;
    const int rbase = h2 * 64 + w * 16;
    #pragma unroll
    for (int ni = 0; ni < 8; ++ni)
      #pragma unroll
      for (int e = 0; e < 4; ++e)
        po[pb + (size_t)(rbase + g * 4 + e) * 128 + ni * 16 + r] = f2bf(o[ni][e]);
    if (r == 0) {
      #pragma unroll
      for (int e = 0; e < 4; ++e)
        pl[((size_t)((b * 16 + t) * 8 + sig)) * 128 + rbase + g * 4 + e] = l[e];
    }
    __syncthreads();
  }
}

// ---- fused epilogue: blocks [0,4096) merge the 8 sigma-partials
//      (skipping q==2047); blocks [4096,4224) write row 2047 = mean(V) ----
__global__ __launch_bounds__(256) void combine(const unsigned short* __restrict__ po,
                                               const float* __restrict__ pl,
                                               const unsigned short* __restrict__ Vt,
                                               float* __restrict__ out) {
  const int bid = blockIdx.x;
  if (bid < 4096) {
    const int idx = bid * 256 + threadIdx.x;   // [0, 1048576)
    const int d = idx & 127;
    const int gq = idx >> 7;          // [0, 8192)
    const int b = gq >> 11, q = gq & 2047;
    if (q == 2047) return;            // written by the lastrow branch
    const int qt = q >> 7, row = q & 127;
    const size_t base = (size_t)(b * 16 + qt) * 8;
    float o = 0.f, l = 0.f;
    #pragma unroll
    for (int s = 0; s < 8; ++s) {
      o += bf2f(po[(base + s) * 16384 + row * 128 + d]);
      l += pl[(base + s) * 128 + row];
    }
    out[idx] = (l > 0.f) ? o / l : 0.f;
  } else {
    // lastrow: mean(V) (reference: all scores -1e9 in fp32 -> uniform softmax)
    const int seg = bid - 4096;       // [0,128)
    const int b = seg >> 5;
    const int w = threadIdx.x >> 6;
    const int lane = threadIdx.x & 63;
    const int dk = (seg & 31) * 4 + w;
    const unsigned short* row = Vt + (size_t)(b * 128 + dk) * 2048;
    float s = 0.f;
    for (int i = lane; i < 2048; i += 64) s += bf2f(row[i]);
    #pragma unroll
    for (int off = 32; off > 0; off >>= 1) s += __shfl_down(s, off, 64);
    if (lane == 0) out[(size_t)(b * 2048 + 2047) * 128 + dk] = s * (1.0f / 2048.0f);
  }
}

extern "C" void kernel_launch(void* const* d_in, const int* in_sizes, int n_in,
                              void* d_out, int out_size, void* d_ws, size_t ws_size,
                              hipStream_t stream) {
  const float* x  = (const float*)d_in[0];
  const float* Wq = (const float*)d_in[1];
  const float* bq = (const float*)d_in[2];
  const float* Wk = (const float*)d_in[3];
  const float* bk = (const float*)d_in[4];
  const float* Wv = (const float*)d_in[5];
  const float* bv = (const float*)d_in[6];
  float* out = (float*)d_out;
  char* ws = (char*)d_ws;
  // workspace layout (bytes), no aliasing:
  //   [16,17MB): Wt | [17,19): Qb | [19,21): Kb | [21,23): Vt
  //   [24,40MB): po (bf16) | [48MB,+64KB): pl (fp32)
  unsigned short* Wt = (unsigned short*)(ws + (size_t)(16u << 20));
  unsigned short* Qb = (unsigned short*)(ws + (size_t)(17u << 20));
  unsigned short* Kb = (unsigned short*)(ws + (size_t)(19u << 20));
  unsigned short* Vt = (unsigned short*)(ws + (size_t)(21u << 20));
  unsigned short* po = (unsigned short*)(ws + (size_t)(24u << 20));
  float* pl = (float*)(ws + (size_t)(48u << 20));

  hipLaunchKernelGGL(cvt_w, dim3(1536), dim3(256), 0, stream, Wq, Wk, Wv, Wt);
  hipLaunchKernelGGL(proj_gemm, dim3(768), dim3(256), 0, stream,
                     x, Wt, bq, bk, bv, Qb, Kb, Vt);
  hipLaunchKernelGGL(attn, dim3(512), dim3(256), 0, stream, Qb, Kb, Vt, po, pl);
  hipLaunchKernelGGL(combine, dim3(4224), dim3(256), 0, stream, po, pl, Vt, out);
}

// Round 25
// 60.888 us; speedup vs baseline: 1.1886x; 1.0075x over previous
//
#include <hip/hip_runtime.h>
#include <hip/hip_bf16.h>

typedef __attribute__((ext_vector_type(8))) short bf16x8;
typedef __attribute__((ext_vector_type(4))) float f32x4;

#define QSCALE 0.088388347648318447f   /* 1/sqrt(128) */

__device__ __forceinline__ unsigned short f2bf(float f) {
  __hip_bfloat16 h = __float2bfloat16(f);
  unsigned short u;
  __builtin_memcpy(&u, &h, 2);
  return u;
}
__device__ __forceinline__ float bf2f(unsigned short u) {
  unsigned int x = ((unsigned int)u) << 16;
  float f; __builtin_memcpy(&f, &x, 4);
  return f;
}

__device__ __forceinline__ void gload_lds16(void* lds, const void* g) {
  __builtin_amdgcn_global_load_lds(
      (const __attribute__((address_space(1))) unsigned int*)g,
      (__attribute__((address_space(3))) unsigned int*)lds, 16, 0, 0);
}

// ---- W^T build only (X conversion folded into proj_gemm) ----
__global__ __launch_bounds__(256) void cvt_w(const float* __restrict__ Wq,
                                             const float* __restrict__ Wk,
                                             const float* __restrict__ Wv,
                                             unsigned short* __restrict__ Wt) {
  int idx = blockIdx.x * 256 + threadIdx.x;   // [0, 393216)
  int n = idx >> 10, d = idx & 1023;
  const float* W = (n < 128) ? Wq : (n < 256 ? Wk : Wv);
  float v = W[d * 128 + (n & 127)];
  if (n < 128) v *= QSCALE;
  Wt[idx] = f2bf(v);
}

// ---- fused QKV projection: fp32 X @ bf16 W^T, 64x64 tile, K_STEP=128 ----
// R24: halve barrier/drain count (16->8 k-iterations); LDS 48KB keeps 3
// blocks/CU (R17/R19: co-residency is what hides the drain). B staged with
// the same source-side XOR swizzle as A (was 16-way read conflict: 128B
// row stride == same bank; chunk == one bf16x8 fragment -> drop-in fix).
// XCD-local mapping kept (mt=bid&127: FETCH 100->19.5MB proven R22).
__global__ __launch_bounds__(256) void proj_gemm(
    const float* __restrict__ X, const unsigned short* __restrict__ Wt,
    const float* __restrict__ bq, const float* __restrict__ bk, const float* __restrict__ bv,
    unsigned short* __restrict__ Qb, unsigned short* __restrict__ Kb,
    unsigned short* __restrict__ Vt) {
  __shared__ float sAf[64 * 128];           // 32KB fp32 A-tile (swizzled)
  __shared__ unsigned short sB[64 * 128];   // 16KB bf16 B-tile (swizzled)
  const int mt = blockIdx.x & 127;
  const int nt = blockIdx.x >> 7;
  const int m0 = mt * 64;
  const int n0 = nt * 64;
  const int tid = threadIdx.x;
  const int lane = tid & 63;
  const int w = tid >> 6;
  const int r = lane & 15, g = lane >> 4;
  const int wm = (w >> 1) * 32, wn = (w & 1) * 32;

  f32x4 acc[2][2];
  #pragma unroll
  for (int mi = 0; mi < 2; ++mi)
    #pragma unroll
    for (int ni = 0; ni < 2; ++ni)
      acc[mi][ni] = (f32x4){0.f, 0.f, 0.f, 0.f};

  const char* Bb = (const char*)Wt;
  char* sAb = (char*)sAf;
  char* sBb = (char*)sB;

  // A staging source (8 chunks/thread): LDS f -> row=f>>9 (512B rows of
  // 128 fp32), chunk c=(f>>4)&31; source float col = (c ^ (row&7))*4.
  int arow_s[8], acol_s[8];
  #pragma unroll
  for (int j = 0; j < 8; ++j) {
    const int f = j * 4096 + tid * 16;
    const int row = f >> 9;
    const int c = (f >> 4) & 31;
    arow_s[j] = row;
    acol_s[j] = (c ^ (row & 7)) * 4;
  }
  // B staging source (4 chunks/thread): row=f>>8 (256B rows of 128 bf16),
  // chunk c=(f>>4)&15; source bf16 col = (c ^ (row&7))*8.
  int brow_s[4], bcol_s[4];
  #pragma unroll
  for (int j = 0; j < 4; ++j) {
    const int f = j * 4096 + tid * 16;
    const int row = f >> 8;
    const int c = (f >> 4) & 15;
    brow_s[j] = row;
    bcol_s[j] = (c ^ (row & 7)) * 8;
  }

  for (int k0 = 0; k0 < 1024; k0 += 128) {
    #pragma unroll
    for (int j = 0; j < 8; ++j)
      gload_lds16(sAb + j * 4096 + tid * 16,
                  X + (size_t)(m0 + arow_s[j]) * 1024 + k0 + acol_s[j]);
    #pragma unroll
    for (int j = 0; j < 4; ++j)
      gload_lds16(sBb + j * 4096 + tid * 16,
                  Bb + ((size_t)(n0 + brow_s[j]) * 1024 + k0 + bcol_s[j]) * 2);
    __syncthreads();
    #pragma unroll
    for (int kk = 0; kk < 4; ++kk) {
      bf16x8 af[2], bfr[2];
      #pragma unroll
      for (int mi = 0; mi < 2; ++mi) {
        const int arow = wm + mi * 16 + r;
        const int sw = arow & 7;
        const int c0 = kk * 8 + g * 2;
        const float4 lo = *reinterpret_cast<const float4*>(
            &sAf[arow * 128 + ((c0 ^ sw) * 4)]);
        const float4 hi = *reinterpret_cast<const float4*>(
            &sAf[arow * 128 + (((c0 + 1) ^ sw) * 4)]);
        union { unsigned short h[8]; bf16x8 v; } u;
        u.h[0] = f2bf(lo.x); u.h[1] = f2bf(lo.y);
        u.h[2] = f2bf(lo.z); u.h[3] = f2bf(lo.w);
        u.h[4] = f2bf(hi.x); u.h[5] = f2bf(hi.y);
        u.h[6] = f2bf(hi.z); u.h[7] = f2bf(hi.w);
        af[mi] = u.v;
      }
      #pragma unroll
      for (int ni = 0; ni < 2; ++ni) {
        const int brow = wn + ni * 16 + r;
        const int cB = (kk * 4 + g) ^ (brow & 7);
        bfr[ni] = *reinterpret_cast<const bf16x8*>(&sB[brow * 128 + cB * 8]);
      }
      #pragma unroll
      for (int mi = 0; mi < 2; ++mi)
        #pragma unroll
        for (int ni = 0; ni < 2; ++ni)
          acc[mi][ni] = __builtin_amdgcn_mfma_f32_16x16x32_bf16(af[mi], bfr[ni], acc[mi][ni], 0, 0, 0);
    }
    __syncthreads();
  }

  const float* bias = (nt < 2) ? bq : (nt < 4 ? bk : bv);
  const float bsc = (nt < 2) ? QSCALE : 1.0f;
  #pragma unroll
  for (int mi = 0; mi < 2; ++mi) {
    #pragma unroll
    for (int ni = 0; ni < 2; ++ni) {
      const int colg = n0 + wn + ni * 16 + r;      // [0,384)
      const int colm = colg & 127;
      const float bias_v = bias[colm] * bsc;
      #pragma unroll
      for (int e = 0; e < 4; ++e) {
        const int row = m0 + wm + mi * 16 + g * 4 + e;   // [0,8192)
        const unsigned short hh = f2bf(acc[mi][ni][e] + bias_v);
        if (nt < 2) Qb[(size_t)row * 128 + colm] = hh;
        else if (nt < 4) Kb[(size_t)row * 128 + colm] = hh;
        else {
          const int bb = row >> 11, s = row & 2047;
          Vt[((size_t)bb * 128 + colm) * 2048 + s] = hh;
        }
      }
    }
  }
}

// ---- flash attention: block-shared LDS-staged K/V (R21 version) ----
__global__ __launch_bounds__(256, 4) void attn(
    const unsigned short* __restrict__ Qb, const unsigned short* __restrict__ Kb,
    const unsigned short* __restrict__ Vt,
    unsigned short* __restrict__ po, float* __restrict__ pl) {
  __shared__ char sK[2][8192];
  __shared__ char sV[2][8192];
  __shared__ unsigned short pbuf_s[4][512];
  const int tid = threadIdx.x;
  const int lane = tid & 63;
  const int w = tid >> 6;                  // [0,4)
  const int r = lane & 15, g = lane >> 4;
  const int sig = blockIdx.x & 7;
  const int b = (blockIdx.x >> 3) & 3;
  const int p = (blockIdx.x >> 5) & 7;     // [0,8)
  const int h2 = blockIdx.x >> 8;          // [0,2)

  const char* Kg = (const char*)(Kb + (size_t)b * 2048 * 128);
  const char* Vg = (const char*)(Vt + (size_t)b * 128 * 2048);
  unsigned short* pbuf = pbuf_s[w];

  const int kr0 = tid >> 4;            // [0,16)
  const int kr1 = 16 + (tid >> 4);     // [16,32)
  const int kc0 = ((tid & 15) * 16) ^ ((kr0 & 7) * 16);
  const int kc1 = ((tid & 15) * 16) ^ ((kr1 & 7) * 16);
  const int vr0 = tid >> 2;            // [0,64)
  const int vr1 = 64 + (tid >> 2);     // [64,128)
  const int vc0 = ((tid & 3) * 16) ^ ((vr0 & 3) * 16);
  const int vc1 = ((tid & 3) * 16) ^ ((vr1 & 3) * 16);

  for (int phase = 0; phase < 2; ++phase) {
    const int t = phase ? (15 - p) : p;
    const int sb = t * 128 + h2 * 64;
    const int ntiles = (2048 - sb) >> 5;
    const int q0w = t * 128 + h2 * 64 + w * 16;

    const unsigned short* Q = Qb + (size_t)(b * 2048 + q0w) * 128;
    bf16x8 qf[4];
    #pragma unroll
    for (int kk = 0; kk < 4; ++kk)
      qf[kk] = *reinterpret_cast<const bf16x8*>(Q + r * 128 + kk * 32 + g * 8);

    f32x4 o[8];
    #pragma unroll
    for (int ni = 0; ni < 8; ++ni) o[ni] = (f32x4){0.f, 0.f, 0.f, 0.f};
    float l[4];
    #pragma unroll
    for (int e = 0; e < 4; ++e) l[e] = 0.f;

    const int nT = (ntiles > sig) ? ((ntiles - sig + 7) >> 3) : 0;

    if (nT > 0) {
      const int s0 = sb + (sig << 5);
      gload_lds16(&sK[0][tid * 16], Kg + (size_t)(s0 + kr0) * 256 + kc0);
      gload_lds16(&sK[0][4096 + tid * 16], Kg + (size_t)(s0 + kr1) * 256 + kc1);
      gload_lds16(&sV[0][tid * 16], Vg + (size_t)vr0 * 4096 + (size_t)s0 * 2 + vc0);
      gload_lds16(&sV[0][4096 + tid * 16], Vg + (size_t)vr1 * 4096 + (size_t)s0 * 2 + vc1);
    }
    for (int it = 0; it < nT; ++it) {
      const int cur = it & 1;
      const int s0 = sb + ((sig + (it << 3)) << 5);
      asm volatile("s_waitcnt vmcnt(0) lgkmcnt(0)" ::: "memory");
      __builtin_amdgcn_sched_barrier(0);
      asm volatile("s_barrier" ::: "memory");
      if (it + 1 < nT) {
        const int s1 = s0 + 256;
        gload_lds16(&sK[cur ^ 1][tid * 16], Kg + (size_t)(s1 + kr0) * 256 + kc0);
        gload_lds16(&sK[cur ^ 1][4096 + tid * 16], Kg + (size_t)(s1 + kr1) * 256 + kc1);
        gload_lds16(&sV[cur ^ 1][tid * 16], Vg + (size_t)vr0 * 4096 + (size_t)s1 * 2 + vc0);
        gload_lds16(&sV[cur ^ 1][4096 + tid * 16], Vg + (size_t)vr1 * 4096 + (size_t)s1 * 2 + vc1);
      }

      f32x4 st[2];
      #pragma unroll
      for (int sj = 0; sj < 2; ++sj) {
        f32x4 a = (f32x4){0.f, 0.f, 0.f, 0.f};
        #pragma unroll
        for (int kk = 0; kk < 4; ++kk) {
          const bf16x8 kf = *reinterpret_cast<const bf16x8*>(
              &sK[cur][(sj * 16 + r) * 256 + (((kk * 64 + g * 16) ^ ((r & 7) * 16)))]);
          a = __builtin_amdgcn_mfma_f32_16x16x32_bf16(qf[kk], kf, a, 0, 0, 0);
        }
        st[sj] = a;
      }
      #pragma unroll
      for (int sj = 0; sj < 2; ++sj) {
        const int s = s0 + sj * 16 + r;
        #pragma unroll
        for (int e = 0; e < 4; ++e) {
          const int q = q0w + g * 4 + e;
          st[sj][e] = (s <= q) ? 0.f : __expf(st[sj][e]);
        }
      }
      #pragma unroll
      for (int e = 0; e < 4; ++e) l[e] += st[0][e] + st[1][e];

      #pragma unroll
      for (int sj = 0; sj < 2; ++sj)
        #pragma unroll
        for (int e = 0; e < 4; ++e)
          pbuf[(g * 4 + e) * 32 + sj * 16 + r] = f2bf(st[sj][e]);
      asm volatile("s_waitcnt lgkmcnt(0)" ::: "memory");
      __builtin_amdgcn_sched_barrier(0);
      const bf16x8 pa = *reinterpret_cast<const bf16x8*>(&pbuf[r * 32 + g * 8]);

      #pragma unroll
      for (int ni = 0; ni < 8; ++ni) {
        const bf16x8 vf = *reinterpret_cast<const bf16x8*>(
            &sV[cur][(ni * 16 + r) * 64 + ((g * 16) ^ ((r & 3) * 16))]);
        o[ni] = __builtin_amdgcn_mfma_f32_16x16x32_bf16(pa, vf, o[ni], 0, 0, 0);
      }
    }

    #pragma unroll
    for (int off = 1; off < 16; off <<= 1)
      #pragma unroll
      for (int e = 0; e < 4; ++e)
        l[e] += __shfl_xor(l[e], off, 64);

    const size_t pb = ((size_t)((b * 16 + t) * 8 + sig)) * 16384;
    const int rbase = h2 * 64 + w * 16;
    #pragma unroll
    for (int ni = 0; ni < 8; ++ni)
      #pragma unroll
      for (int e = 0; e < 4; ++e)
        po[pb + (size_t)(rbase + g * 4 + e) * 128 + ni * 16 + r] = f2bf(o[ni][e]);
    if (r == 0) {
      #pragma unroll
      for (int e = 0; e < 4; ++e)
        pl[((size_t)((b * 16 + t) * 8 + sig)) * 128 + rbase + g * 4 + e] = l[e];
    }
    __syncthreads();
  }
}

// ---- fused epilogue: blocks [0,4096) merge the 8 sigma-partials
//      (skipping q==2047); blocks [4096,4224) write row 2047 = mean(V) ----
__global__ __launch_bounds__(256) void combine(const unsigned short* __restrict__ po,
                                               const float* __restrict__ pl,
                                               const unsigned short* __restrict__ Vt,
                                               float* __restrict__ out) {
  const int bid = blockIdx.x;
  if (bid < 4096) {
    const int idx = bid * 256 + threadIdx.x;   // [0, 1048576)
    const int d = idx & 127;
    const int gq = idx >> 7;          // [0, 8192)
    const int b = gq >> 11, q = gq & 2047;
    if (q == 2047) return;            // written by the lastrow branch
    const int qt = q >> 7, row = q & 127;
    const size_t base = (size_t)(b * 16 + qt) * 8;
    float o = 0.f, l = 0.f;
    #pragma unroll
    for (int s = 0; s < 8; ++s) {
      o += bf2f(po[(base + s) * 16384 + row * 128 + d]);
      l += pl[(base + s) * 128 + row];
    }
    out[idx] = (l > 0.f) ? o / l : 0.f;
  } else {
    // lastrow: mean(V) (reference: all scores -1e9 in fp32 -> uniform softmax)
    const int seg = bid - 4096;       // [0,128)
    const int b = seg >> 5;
    const int w = threadIdx.x >> 6;
    const int lane = threadIdx.x & 63;
    const int dk = (seg & 31) * 4 + w;
    const unsigned short* row = Vt + (size_t)(b * 128 + dk) * 2048;
    float s = 0.f;
    for (int i = lane; i < 2048; i += 64) s += bf2f(row[i]);
    #pragma unroll
    for (int off = 32; off > 0; off >>= 1) s += __shfl_down(s, off, 64);
    if (lane == 0) out[(size_t)(b * 2048 + 2047) * 128 + dk] = s * (1.0f / 2048.0f);
  }
}

extern "C" void kernel_launch(void* const* d_in, const int* in_sizes, int n_in,
                              void* d_out, int out_size, void* d_ws, size_t ws_size,
                              hipStream_t stream) {
  const float* x  = (const float*)d_in[0];
  const float* Wq = (const float*)d_in[1];
  const float* bq = (const float*)d_in[2];
  const float* Wk = (const float*)d_in[3];
  const float* bk = (const float*)d_in[4];
  const float* Wv = (const float*)d_in[5];
  const float* bv = (const float*)d_in[6];
  float* out = (float*)d_out;
  char* ws = (char*)d_ws;
  // workspace layout (bytes), no aliasing:
  //   [16,17MB): Wt | [17,19): Qb | [19,21): Kb | [21,23): Vt
  //   [24,40MB): po (bf16) | [48MB,+64KB): pl (fp32)
  unsigned short* Wt = (unsigned short*)(ws + (size_t)(16u << 20));
  unsigned short* Qb = (unsigned short*)(ws + (size_t)(17u << 20));
  unsigned short* Kb = (unsigned short*)(ws + (size_t)(19u << 20));
  unsigned short* Vt = (unsigned short*)(ws + (size_t)(21u << 20));
  unsigned short* po = (unsigned short*)(ws + (size_t)(24u << 20));
  float* pl = (float*)(ws + (size_t)(48u << 20));

  hipLaunchKernelGGL(cvt_w, dim3(1536), dim3(256), 0, stream, Wq, Wk, Wv, Wt);
  hipLaunchKernelGGL(proj_gemm, dim3(768), dim3(256), 0, stream,
                     x, Wt, bq, bk, bv, Qb, Kb, Vt);
  hipLaunchKernelGGL(attn, dim3(512), dim3(256), 0, stream, Qb, Kb, Vt, po, pl);
  hipLaunchKernelGGL(combine, dim3(4224), dim3(256), 0, stream, po, pl, Vt, out);
}